// Round 7
// baseline (911014.355 us; speedup 1.0000x reference)
//
#include <hip/hip_runtime.h>
#include <hip/hip_bf16.h>
#include <stdint.h>

// LSTM persistent kernel, round 7: XCD-local sync domains.
// T=2048, B=64, I=512, H=512.
// 256 blocks (1/CU forced via LDS pad) = 8 groups x 32 blocks. Group g owns
// batches [8g,8g+8); block slot owns 16 h-cols. Groups are formed by MEASURED
// XCD residency (HW_REG_XCC_ID + roster claim + one-time grid barrier). If
// every XCD has exactly 32 blocks: per-step sync runs entirely in the XCD's
// L2 (plain stores, sc0 loads, unscoped atomic_add) -> ~10x lower hop latency
// than the L3/fabric path. Otherwise: fall back to the round-6-proven
// agent-scope (sc0 sc1) protocol with ticket-based groups (correct on any
// placement). Round 6 falsified the contention theory (layout change = 0.2%);
// this round attacks hop LATENCY by moving the coherence point.

#define T_STEPS 2048
#define BATCH   64
#define HDIM    512

typedef __attribute__((ext_vector_type(8))) short  vshort8;
typedef __attribute__((ext_vector_type(4))) float  vfloat4;

__device__ __forceinline__ unsigned short f2bf(float f) {
  unsigned int u = __builtin_bit_cast(unsigned int, f);
  u += 0x7fffu + ((u >> 16) & 1u);          // round-to-nearest-even
  return (unsigned short)(u >> 16);
}

__device__ __forceinline__ vfloat4 mfma_bf16(vshort8 a, vshort8 b, vfloat4 c) {
  asm("v_mfma_f32_16x16x32_bf16 %0, %1, %2, %0" : "+v"(c) : "v"(a), "v"(b));
  return c;
}

__device__ __forceinline__ float sigmoid_(float x) {
  return 1.0f / (1.0f + __expf(-x));
}
__device__ __forceinline__ float tanh_(float x) {
  float ax = fabsf(x);
  float t  = __expf(-2.0f * ax);
  float y  = (1.0f - t) / (1.0f + t);
  return x < 0.0f ? -y : y;
}

__device__ __forceinline__ unsigned agent_add(unsigned* p, unsigned v) {
  return __hip_atomic_fetch_add(p, v, __ATOMIC_RELAXED, __HIP_MEMORY_SCOPE_AGENT);
}
__device__ __forceinline__ unsigned agent_ld(const unsigned* p) {
  return __hip_atomic_load(p, __ATOMIC_RELAXED, __HIP_MEMORY_SCOPE_AGENT);
}

// ws layout (bytes):
//   [0,     4096)  ctrl:  roster[x] @ uint x*32 (x=0..7), ticket @ uint 256,
//                         arrive @ uint 288
//   [4096, 36864)  flags: uint index (group*32+slot)*32   (128 B lines)
//   [36864,167936) hbuf:  ushort; region(g,b,q) = ((g*2+b)*32+q)*128 ushorts
//                         region = [8 rows][16 cols] bf16 (256 B)
__global__ void lstm_zero_ws(unsigned int* ws) {
  const int i = blockIdx.x * 256 + threadIdx.x;
  if (i < 41984) ws[i] = 0u;   // 167936/4
}

__global__ __launch_bounds__(256, 1)
void lstm_persistent(const float* __restrict__ word_seq,
                     const float* __restrict__ w_ih,
                     const float* __restrict__ w_hh,
                     const float* __restrict__ b_ih,
                     const float* __restrict__ b_hh,
                     float* __restrict__ out,
                     unsigned int* __restrict__ ctrl,
                     unsigned int* __restrict__ flags,
                     unsigned short* __restrict__ hbuf) {
  __shared__ unsigned short x_s[8][520];     // 8 batch rows x 512 (+8 pad)
  __shared__ float red[4][4][16][12];        // [wave][gate][col][row(8)+pad]
  __shared__ unsigned disc[3];
  __shared__ char lds_pad[65536];            // forces 1 block/CU (LDS > 80 KB)

  const int tid  = threadIdx.x;
  const int wv   = tid >> 6;    // wave 0..3: K-window [wv*128, wv*128+128)
  const int lane = tid & 63;
  const int mrow = lane & 15;   // A-row / B-col lane index (rows >=8 are zero)
  const int g4   = lane >> 4;   // k-group 0..3

  // keep the pad array alive (condition is never true, not provable)
  if (__builtin_amdgcn_workgroup_id_x() == 0xFFFFFFFFu)
    ((volatile char*)lds_pad)[tid] = 1;

  // ---------- discovery: measured XCD residency + one-time grid barrier ----
  if (tid == 0) {
    // hwreg(HW_REG_XCC_ID=20, offset 0, size 32)  [measured: learn_hip m09]
    unsigned xcd = __builtin_amdgcn_s_getreg((31u << 11) | 20u) & 7u;
    unsigned xr = agent_add(&ctrl[xcd * 32], 1u);
    unsigned tr = agent_add(&ctrl[256], 1u);
    asm volatile("s_waitcnt vmcnt(0)" ::: "memory");  // roster adds land first
    agent_add(&ctrl[288], 1u);
    int guard = 0;
    while (agent_ld(&ctrl[288]) < 256u) { if (++guard > (1 << 20)) break; }
    bool ok = true;
    for (int i = 0; i < 8; ++i) ok = ok && (agent_ld(&ctrl[i * 32]) == 32u);
    ok = ok && (xr < 32u);
    disc[0] = ok ? xcd : (tr >> 5);
    disc[1] = ok ? xr  : (tr & 31u);
    disc[2] = ok ? 1u  : 0u;
  }
  __syncthreads();
  const int  group = (int)disc[0];
  const int  slot  = (int)disc[1];
  const bool l2m   = disc[2] != 0u;   // uniform across the whole grid

  // ---------- weight B-fragments (bf16) into registers, once ----------
  // B[k][n] = W[gc(n)][k]; k = wv*128 + kk*32 + g4*8 + j (same k-hat as A)
  vshort8 bw[2][4][4];
#pragma unroll
  for (int p = 0; p < 2; ++p) {
    const float* W = p ? w_hh : w_ih;
#pragma unroll
    for (int n = 0; n < 4; ++n) {
      const int gc = n * 512 + slot * 16 + mrow;
#pragma unroll
      for (int kk = 0; kk < 4; ++kk) {
        const int k0 = wv * 128 + kk * 32 + g4 * 8;
        const float* src = W + (size_t)gc * 512 + k0;
        vshort8 fr;
#pragma unroll
        for (int j = 0; j < 8; ++j) fr[j] = (short)f2bf(src[j]);
        bw[p][n][kk] = fr;
      }
    }
  }

  // ---------- activation-stage ownership: threads 0..63, 1 row x 2 cols ----
  const int arow = tid >> 3;          // 0..7 (valid when tid<64)
  const int aom  = (tid & 7) * 2;     // 0,2,..,14

  float bsum[4][2];
  if (tid < 64) {
#pragma unroll
    for (int n = 0; n < 4; ++n)
#pragma unroll
      for (int e = 0; e < 2; ++e) {
        const int gc = n * 512 + slot * 16 + aom + e;
        bsum[n][e] = b_ih[gc] + b_hh[gc];
      }
  }
  float cst[2]   = {0.0f, 0.0f};
  float hlast[2] = {0.0f, 0.0f};

  // ---------- stage x_0 (wave-local k-window) ----------
#pragma unroll
  for (int it = 0; it < 4; ++it) {
    const int idx = it * 64 + lane;          // 0..255
    const int row = idx >> 5;                // 0..7
    const int col = wv * 128 + (idx & 31) * 4;
    const float4 v = *(const float4*)(word_seq +
        ((size_t)group * 8 + row) * 512 + col);
    ushort4 us;
    us.x = f2bf(v.x); us.y = f2bf(v.y); us.z = f2bf(v.z); us.w = f2bf(v.w);
    *(ushort4*)&x_s[row][col] = us;
  }

  unsigned* myflag = &flags[(group * 32 + slot) * 32];
  unsigned* pollp  = &flags[(group * 32 + (lane & 31)) * 32];

  // ===================== main sequential loop =====================
#pragma unroll 1
  for (int t = 0; t < T_STEPS; ++t) {
    // ---- h_{t-1} fragments (issued early; waited after x-MFMA) ----
    vshort8 hfr[4];
    if (t > 0) {
      const unsigned short* hb =
          hbuf + (size_t)((group * 2 + ((t - 1) & 1)) * 32) * 128;
#pragma unroll
      for (int kk = 0; kk < 4; ++kk) {
        const int kb = wv * 128 + kk * 32 + g4 * 8;
        const unsigned short* p = hb + (kb >> 4) * 128 + mrow * 16 + (kb & 15);
        if (mrow < 8) {
          if (l2m) {
            asm volatile("global_load_dwordx4 %0, %1, off sc0"
                         : "=v"(hfr[kk]) : "v"(p) : "memory");
          } else {
            union { struct { unsigned long long lo, hi; } q; vshort8 v; } u;
            u.q.lo = __hip_atomic_load((const unsigned long long*)p,
                        __ATOMIC_RELAXED, __HIP_MEMORY_SCOPE_AGENT);
            u.q.hi = __hip_atomic_load(((const unsigned long long*)p) + 1,
                        __ATOMIC_RELAXED, __HIP_MEMORY_SCOPE_AGENT);
            hfr[kk] = u.v;
          }
        } else {
          hfr[kk] = (vshort8)0;
        }
      }
    }

    // ---- x-part MFMA from LDS (overlaps h-load latency) ----
    vfloat4 acc[4];
#pragma unroll
    for (int n = 0; n < 4; ++n) acc[n] = (vfloat4)0.0f;
#pragma unroll
    for (int kk = 0; kk < 4; ++kk) {
      const int kb = wv * 128 + kk * 32 + g4 * 8;
      const vshort8 a =
          (mrow < 8) ? *(const vshort8*)&x_s[mrow][kb] : (vshort8)0;
#pragma unroll
      for (int n = 0; n < 4; ++n) acc[n] = mfma_bf16(a, bw[0][n][kk], acc[n]);
    }

    // ---- h-part MFMA ----
    if (t > 0) {
      if (l2m) {
        // asm loads are invisible to the compiler's waitcnt logic:
        // explicit drain + sched fence (rule #18) before consuming hfr.
        asm volatile("s_waitcnt vmcnt(0)" ::: "memory");
        __builtin_amdgcn_sched_barrier(0);
      }
#pragma unroll
      for (int kk = 0; kk < 4; ++kk)
#pragma unroll
        for (int n = 0; n < 4; ++n)
          acc[n] = mfma_bf16(hfr[kk], bw[1][n][kk], acc[n]);
    }

    // MFMA->VALU/DS hazard guard (inline-asm MFMA bypasses hazard recognizer)
    asm volatile("s_nop 7\n\ts_nop 7" ::: "memory");

    // ---- per-wave partials; D rows 0..7 live in lanes g4<2 ----
    if (g4 < 2) {
#pragma unroll
      for (int n = 0; n < 4; ++n)
        *(vfloat4*)&red[wv][n][mrow][g4 * 4] = acc[n];
    }
    __syncthreads();                                   // sync 1

    // ---- reduce + activations + state (threads 0..63) ----
    float hv0 = 0.0f, hv1 = 0.0f;
    if (tid < 64) {
      float g[4][2];
#pragma unroll
      for (int n = 0; n < 4; ++n) {
        float s0 = bsum[n][0], s1 = bsum[n][1];
#pragma unroll
        for (int w2 = 0; w2 < 4; ++w2) {
          s0 += red[w2][n][aom][arow];
          s1 += red[w2][n][aom + 1][arow];
        }
        g[n][0] = s0; g[n][1] = s1;
      }
#pragma unroll
      for (int e = 0; e < 2; ++e) {
        const float ig = sigmoid_(g[0][e]);
        const float fg = sigmoid_(g[1][e]);
        const float gg = tanh_(g[2][e]);
        const float og = sigmoid_(g[3][e]);
        cst[e] = fg * cst[e] + ig * gg;
        const float hv = og * tanh_(cst[e]);
        if (e == 0) hv0 = hv; else hv1 = hv;
      }
      hlast[0] = hv0; hlast[1] = hv1;

      // publish h slice (4B packed) into this block's producer region
      const unsigned packed =
          (unsigned)f2bf(hv0) | ((unsigned)f2bf(hv1) << 16);
      unsigned short* hp = hbuf +
          (size_t)((group * 2 + (t & 1)) * 32 + slot) * 128 + arow * 16 + aom;
      if (l2m) {
        *(unsigned*)hp = packed;                       // plain -> lands in L2
      } else {
        asm volatile("global_store_dword %0, %1, off sc0 sc1"
                     :: "v"(hp), "v"(packed) : "memory");
      }
    }

    // drain h stores to the coherence point, then barrier, then arrival
    asm volatile("s_waitcnt vmcnt(0)" ::: "memory");
    __syncthreads();                                   // sync 2
    if (tid == 0) {
      if (l2m)
        asm volatile("global_atomic_add %0, %1, off"   // L2-point RMW
                     :: "v"(myflag), "v"(1u) : "memory");
      else
        agent_add(myflag, 1u);
    }

    // out[t] store AFTER the flag (off the inter-block critical path)
    if (tid < 64) {
      float2 h2; h2.x = hv0; h2.y = hv1;
      *(float2*)&out[((size_t)t * BATCH + group * 8 + arow) * 512 +
                     slot * 16 + aom] = h2;
    }

    if (t + 1 < T_STEPS) {
      // stage x_{t+1} (wave-local) while other blocks arrive
#pragma unroll
      for (int it = 0; it < 4; ++it) {
        const int idx = it * 64 + lane;
        const int row = idx >> 5;
        const int col = wv * 128 + (idx & 31) * 4;
        const float4 v = *(const float4*)(word_seq +
            ((size_t)(t + 1) * BATCH + group * 8 + row) * 512 + col);
        ushort4 us;
        us.x = f2bf(v.x); us.y = f2bf(v.y); us.z = f2bf(v.z); us.w = f2bf(v.w);
        *(ushort4*)&x_s[row][col] = us;
      }
      // spin: lane l watches producer line l&31 (ballot exit)
      const unsigned target = (unsigned)(t + 1);
      if (l2m) {
        int guard = 0;
        for (;;) {
          unsigned v;
          asm volatile("global_load_dword %0, %1, off sc0\n\t"
                       "s_waitcnt vmcnt(0)"
                       : "=v"(v) : "v"(pollp) : "memory");
          if (__ballot(v < target) == 0ull) break;
          if (++guard > (1 << 12)) break;  // failsafe: wrong beats hang
        }
      } else {
        int guard = 0;
        for (;;) {
          const unsigned v = agent_ld(pollp);
          if (__ballot(v < target) == 0ull) break;
          if (++guard > (1 << 16)) break;
        }
      }
      asm volatile("" ::: "memory");       // no h load hoisted above the spin
    }
  }

  // ---------- tails: final h and c (fp32) ----------
  if (tid < 64) {
    const size_t tail = (size_t)T_STEPS * BATCH * HDIM;
    const size_t gb   = (size_t)group * 8 + arow;
    const int    col  = slot * 16 + aom;
    float2 h2; h2.x = hlast[0]; h2.y = hlast[1];
    float2 c2; c2.x = cst[0];   c2.y = cst[1];
    *(float2*)&out[tail + gb * 512 + col] = h2;
    *(float2*)&out[tail + (size_t)BATCH * HDIM + gb * 512 + col] = c2;
  }
}

extern "C" void kernel_launch(void* const* d_in, const int* in_sizes, int n_in,
                              void* d_out, int out_size, void* d_ws, size_t ws_size,
                              hipStream_t stream) {
  (void)in_sizes; (void)n_in; (void)out_size; (void)ws_size;
  const float* word_seq = (const float*)d_in[0];
  const float* w_ih     = (const float*)d_in[1];
  const float* w_hh     = (const float*)d_in[2];
  const float* b_ih     = (const float*)d_in[3];
  const float* b_hh     = (const float*)d_in[4];
  float* out = (float*)d_out;

  unsigned int*   ctrl  = (unsigned int*)d_ws;
  unsigned int*   flags = ctrl + 1024;                          // +4 KB
  unsigned short* hbuf  = (unsigned short*)((char*)d_ws + 36864);

  lstm_zero_ws<<<164, 256, 0, stream>>>((unsigned int*)d_ws);   // 41984 uints
  lstm_persistent<<<256, 256, 0, stream>>>(word_seq, w_ih, w_hh, b_ih, b_hh,
                                           out, ctrl, flags, hbuf);
}

// Round 8
// 21732.719 us; speedup vs baseline: 41.9190x; 41.9190x over previous
//
#include <hip/hip_runtime.h>
#include <hip/hip_bf16.h>
#include <stdint.h>

// LSTM persistent kernel, round 8: self-signaling h (generation tag in the
// bf16 mantissa LSB) -> the h data poll IS the sync. Removes the r6 chain's
// store-drain, flag RMW, and detect hops (4 agent hops -> ~1.5).
// Since |h| < 1 strictly, forcing each stored bf16's LSB to
// gen(t) = ((t>>1)&1)^1 costs <= 1 ulp and makes zero-init + stale data
// structurally invalid. Consumers spin on agent-relaxed atomic loads (the
// ONLY load class proven to observe remote writes on this chip: r2/r6
// passed, r7's sc0-only polls were served stale from L1 -> guard-break
// pacing, 911 ms). Everything else is byte-identical to the r6 kernel.
// T=2048, B=64, I=512, H=512.
// 64 blocks = 2 batch-groups x 32 col-groups; block owns 32 batches x 16 h-cols.

#define T_STEPS 2048
#define BATCH   64
#define IDIM    512
#define HDIM    512

typedef __attribute__((ext_vector_type(8))) short  vshort8;
typedef __attribute__((ext_vector_type(4))) float  vfloat4;

__device__ __forceinline__ unsigned short f2bf(float f) {
  unsigned int u = __builtin_bit_cast(unsigned int, f);
  u += 0x7fffu + ((u >> 16) & 1u);          // round-to-nearest-even
  return (unsigned short)(u >> 16);
}

__device__ __forceinline__ vfloat4 mfma_bf16(vshort8 a, vshort8 b, vfloat4 c) {
  asm("v_mfma_f32_16x16x32_bf16 %0, %1, %2, %0" : "+v"(c) : "v"(a), "v"(b));
  return c;
}

__device__ __forceinline__ float sigmoid_(float x) {
  return 1.0f / (1.0f + __expf(-x));
}
__device__ __forceinline__ float tanh_(float x) {
  float ax = fabsf(x);
  float t  = __expf(-2.0f * ax);
  float y  = (1.0f - t) / (1.0f + t);
  return x < 0.0f ? -y : y;
}

// zero flags region (unused this round, kept for layout) + hbuf:
// 34816 uints = 8 KB + 128 KB. Zeroed hbuf has LSB=0 everywhere, which can
// never match gen(t) in {1,1,0,0,...} for the first use of each buffer.
__global__ void lstm_zero_ws(unsigned int* ws) {
  const int i = blockIdx.x * 256 + threadIdx.x;
  if (i < 34816) ws[i] = 0u;
}

__global__ __launch_bounds__(256, 1)
void lstm_persistent(const float* __restrict__ word_seq,
                     const float* __restrict__ w_ih,
                     const float* __restrict__ w_hh,
                     const float* __restrict__ b_ih,
                     const float* __restrict__ b_hh,
                     float* __restrict__ out,
                     unsigned short* __restrict__ hbuf) {
  // x tile: 32 rows x 512 cols bf16 (+8 pad). red = cross-wave K-reduction.
  __shared__ unsigned short x_s[32][520];
  __shared__ float red[4][2][4][16][20];   // [wave][rowtile][gate][dcol][drow+pad]

  const int tid  = threadIdx.x;
  const int blk  = blockIdx.x;
  const int bg   = blk >> 5;   // batch group: batches [bg*32, bg*32+32)
  const int cg   = blk & 31;   // col group:   h-cols  [cg*16, cg*16+16)
  const int wv   = tid >> 6;   // wave 0..3 (K-split)
  const int lane = tid & 63;
  const int mrow = lane & 15;  // A-row / B-col lane index
  const int g4   = lane >> 4;  // k-group 0..3

  // ------- weight B-fragments (bf16) into registers, once -------
  // B[k][n] = W[gc(n)][k]; k = wv*128 + kk*32 + g4*8 + j (same k-hat as A frags)
  vshort8 bw[2][4][4];
#pragma unroll
  for (int p = 0; p < 2; ++p) {
    const float* W = p ? w_hh : w_ih;
#pragma unroll
    for (int n = 0; n < 4; ++n) {
      const int gc = n * 512 + cg * 16 + mrow;
#pragma unroll
      for (int kk = 0; kk < 4; ++kk) {
        const int k0 = wv * 128 + kk * 32 + g4 * 8;
        const float* src = W + (size_t)gc * 512 + k0;
        vshort8 fr;
#pragma unroll
        for (int j = 0; j < 8; ++j) fr[j] = (short)f2bf(src[j]);
        bw[p][n][kk] = fr;
      }
    }
  }

  // ------- per-thread output ownership: 2 adjacent h-cols of one batch row -------
  const int orow = tid >> 3;           // batch-local row 0..31
  const int om   = (tid & 7) * 2;      // even local col in n-tile, 0..14
  const int ort  = orow >> 4;          // row tile
  const int odr  = orow & 15;          // d-row within tile

  float bsum[4][2];
#pragma unroll
  for (int n = 0; n < 4; ++n)
#pragma unroll
    for (int e = 0; e < 2; ++e) {
      const int gc = n * 512 + cg * 16 + om + e;
      bsum[n][e] = b_ih[gc] + b_hh[gc];
    }

  float cst[2]   = {0.0f, 0.0f};
  float hlast[2] = {0.0f, 0.0f};

  // ------- stage x_0 (wave-local k-window: cols [wv*128, wv*128+128)) -------
#pragma unroll
  for (int it = 0; it < 16; ++it) {
    const int idx = it * 64 + lane;          // 0..1023
    const int row = idx >> 5;                // 0..31
    const int c4  = idx & 31;                // float4 index within window
    const int col = wv * 128 + c4 * 4;
    const float4 v = *(const float4*)(word_seq + ((size_t)bg * 32 + row) * 512 + col);
    ushort4 us;
    us.x = f2bf(v.x); us.y = f2bf(v.y); us.z = f2bf(v.z); us.w = f2bf(v.w);
    *(ushort4*)&x_s[row][col] = us;
  }

  // ===================== main sequential loop =====================
#pragma unroll 1
  for (int t = 0; t < T_STEPS; ++t) {
    // ---- x-part MFMA from LDS (wave-own k-window)
    vfloat4 acc[2][4];
#pragma unroll
    for (int r = 0; r < 2; ++r)
#pragma unroll
      for (int n = 0; n < 4; ++n) acc[r][n] = (vfloat4)0.0f;

#pragma unroll
    for (int kk = 0; kk < 4; ++kk) {
      const int kb = wv * 128 + kk * 32 + g4 * 8;
      const vshort8 a0 = *(const vshort8*)&x_s[mrow][kb];
      const vshort8 a1 = *(const vshort8*)&x_s[16 + mrow][kb];
#pragma unroll
      for (int n = 0; n < 4; ++n) {
        acc[0][n] = mfma_bf16(a0, bw[0][n][kk], acc[0][n]);
        acc[1][n] = mfma_bf16(a1, bw[0][n][kk], acc[1][n]);
      }
    }

    if (t > 0) {
      // ---- poll-fused h_{t-1} load: retry until every packed word carries
      //      the expected generation tag in BOTH bf16 LSBs.
      const unsigned gr = (((unsigned)(t - 1) >> 1) & 1u) ^ 1u;  // expected gen
      const unsigned short* hbR =
          hbuf + ((size_t)((t - 1) & 1) * BATCH + bg * 32) * 512;
      vshort8 hfr[2][4];
      unsigned bad = 1u;
      int guard = 0;
      while (__ballot(bad != 0u) != 0ull) {
        if (bad) {
          bad = 0u;
#pragma unroll
          for (int r = 0; r < 2; ++r)
#pragma unroll
            for (int kk = 0; kk < 4; ++kk) {
              const int kb = wv * 128 + kk * 32 + g4 * 8;
              const unsigned long long* p =
                  (const unsigned long long*)(hbR + (r * 16 + mrow) * 512 + kb);
              union { struct { unsigned long long lo, hi; } q; vshort8 v; } u;
              u.q.lo = __hip_atomic_load(p,     __ATOMIC_RELAXED,
                                         __HIP_MEMORY_SCOPE_AGENT);
              u.q.hi = __hip_atomic_load(p + 1, __ATOMIC_RELAXED,
                                         __HIP_MEMORY_SCOPE_AGENT);
              hfr[r][kk] = u.v;
              const unsigned w0 = (unsigned)u.q.lo;
              const unsigned w1 = (unsigned)(u.q.lo >> 32);
              const unsigned w2 = (unsigned)u.q.hi;
              const unsigned w3 = (unsigned)(u.q.hi >> 32);
              // word valid iff (w&1)==gr and ((w>>16)&1)==gr
              bad |= (((w0 ^ (w0 >> 16)) & 1u) | ((w0 & 1u) ^ gr));
              bad |= (((w1 ^ (w1 >> 16)) & 1u) | ((w1 & 1u) ^ gr));
              bad |= (((w2 ^ (w2 >> 16)) & 1u) | ((w2 & 1u) ^ gr));
              bad |= (((w3 ^ (w3 >> 16)) & 1u) | ((w3 & 1u) ^ gr));
            }
        }
        if (++guard > (1 << 14)) break;   // failsafe: wrong answer beats a hang
      }
      asm volatile("" ::: "memory");

      // ---- h-part MFMA (hfr delivered by the successful poll iteration)
#pragma unroll
      for (int kk = 0; kk < 4; ++kk)
#pragma unroll
        for (int n = 0; n < 4; ++n) {
          acc[0][n] = mfma_bf16(hfr[0][kk], bw[1][n][kk], acc[0][n]);
          acc[1][n] = mfma_bf16(hfr[1][kk], bw[1][n][kk], acc[1][n]);
        }
    }

    // MFMA->VALU/DS hazard guard (inline-asm MFMA bypasses hazard recognizer)
    asm volatile("s_nop 7\n\ts_nop 7" ::: "memory");

    // ---- per-wave partials; D layout: col=lane&15, row=(lane>>4)*4+reg
#pragma unroll
    for (int r = 0; r < 2; ++r)
#pragma unroll
      for (int n = 0; n < 4; ++n)
        *(vfloat4*)&red[wv][r][n][mrow][g4 * 4] = acc[r][n];
    __syncthreads();                                     // sync 1

    // ---- reduce across waves + bias
    float gate[4][2];
#pragma unroll
    for (int n = 0; n < 4; ++n) {
      float s0 = bsum[n][0], s1 = bsum[n][1];
#pragma unroll
      for (int w2 = 0; w2 < 4; ++w2) {
        s0 += red[w2][ort][n][om][odr];
        s1 += red[w2][ort][n][om + 1][odr];
      }
      gate[n][0] = s0; gate[n][1] = s1;
    }
    __syncthreads();   // sync 2: red reads complete before next-iter red writes

    // ---- activations, state update
    float hv[2];
#pragma unroll
    for (int e = 0; e < 2; ++e) {
      const float ig = sigmoid_(gate[0][e]);
      const float fg = sigmoid_(gate[1][e]);
      const float gg = tanh_(gate[2][e]);
      const float og = sigmoid_(gate[3][e]);
      cst[e] = fg * cst[e] + ig * gg;
      hv[e]  = og * tanh_(cst[e]);
    }
    hlast[0] = hv[0]; hlast[1] = hv[1];

    // ---- publish h with generation tag in each bf16 LSB (<=1 ulp distortion)
    {
      const unsigned gw = (((unsigned)t >> 1) & 1u) ^ 1u;
      unsigned u0 = f2bf(hv[0]);  u0 += ((u0 & 1u) ^ gw);
      unsigned u1 = f2bf(hv[1]);  u1 += ((u1 & 1u) ^ gw);
      const unsigned packed = (u0 & 0xffffu) | (u1 << 16);
      unsigned int* hbW = (unsigned int*)(hbuf +
          ((size_t)(t & 1) * BATCH + bg * 32) * 512 + orow * 512 + cg * 16 + om);
      __hip_atomic_store(hbW, packed, __ATOMIC_RELAXED, __HIP_MEMORY_SCOPE_AGENT);

      float2 h2; h2.x = hv[0]; h2.y = hv[1];
      *(float2*)&out[((size_t)t * BATCH + bg * 32 + orow) * 512 + cg * 16 + om] = h2;
    }

    // ---- stage x_{t+1} (wave-local slice); overlaps peers' publish latency
    if (t + 1 < T_STEPS) {
#pragma unroll
      for (int it = 0; it < 16; ++it) {
        const int idx = it * 64 + lane;
        const int row = idx >> 5;
        const int c4  = idx & 31;
        const int col = wv * 128 + c4 * 4;
        const float4 v = *(const float4*)(word_seq +
            ((size_t)(t + 1) * BATCH + bg * 32 + row) * 512 + col);
        ushort4 us;
        us.x = f2bf(v.x); us.y = f2bf(v.y); us.z = f2bf(v.z); us.w = f2bf(v.w);
        *(ushort4*)&x_s[row][col] = us;
      }
    }
  }

  // ------- tails: final h and c (fp32) -------
  {
    const size_t tail = (size_t)T_STEPS * BATCH * HDIM;
    const size_t gb   = (size_t)bg * 32 + orow;
    const int    col  = cg * 16 + om;
    float2 h2; h2.x = hlast[0]; h2.y = hlast[1];
    float2 c2; c2.x = cst[0];   c2.y = cst[1];
    *(float2*)&out[tail + gb * 512 + col] = h2;
    *(float2*)&out[tail + (size_t)BATCH * HDIM + gb * 512 + col] = c2;
  }
}

extern "C" void kernel_launch(void* const* d_in, const int* in_sizes, int n_in,
                              void* d_out, int out_size, void* d_ws, size_t ws_size,
                              hipStream_t stream) {
  (void)in_sizes; (void)n_in; (void)out_size; (void)ws_size;
  const float* word_seq = (const float*)d_in[0];
  const float* w_ih     = (const float*)d_in[1];
  const float* w_hh     = (const float*)d_in[2];
  const float* b_ih     = (const float*)d_in[3];
  const float* b_hh     = (const float*)d_in[4];
  float* out = (float*)d_out;

  unsigned short* hbuf = (unsigned short*)((char*)d_ws + 8192);

  lstm_zero_ws<<<136, 256, 0, stream>>>((unsigned int*)d_ws);  // flags + hbuf
  lstm_persistent<<<64, 256, 0, stream>>>(word_seq, w_ih, w_hh, b_ih, b_hh,
                                          out, hbuf);
}